// Round 8
// baseline (229.091 us; speedup 1.0000x reference)
//
#include <hip/hip_runtime.h>
#include <hip/hip_cooperative_groups.h>

// CIN fully fused, d-contraction-first. R15: pack_w folded INTO cin as a
// prologue (cooperative launch + grid.sync). Each of 256 blocks packs a
// balanced 1/256 W-slice (half a w0 row + half a w1 row, ~13KB coalesced)
// overlapped with x-staging, then __threadfence + grid.sync (device-scope
// release/acquire covers cross-XCD L2 visibility), then phases 1-3 = R12.
// Kills the separate pack kernel's serial window + launch gap, and makes
// the compute kernel visible in top-5 counters again (~45us > 41.5 fill
// cutoff). Fallback: classic pack+cin pair if cooperative launch errors.
//   out1[b,h] = sum_d h1[b,h,d];  h1 = sum_{f,q} W0[h,fq] x[b,f,d] x[b,q,d]
//   out2[b,h] = sum_p W1[h,p] U[b,p];  U[b,(f,q)] = sum_d x[b,f,d] h1[b,q,d]
// 256 blocks x 1024 thr, 1 block/CU, ~140KB LDS, fp16 datapath.

namespace cg = cooperative_groups;

#define F0   39
#define D_   16
#define H_   128
#define P0_  1521
#define P1_  4992
#define G8   8
#define NF1  (F0 * 3 * 4)   // 468 layer-1 A-frags (f x ks x mt), 32x32x16
#define NF2  (F0 * 4 * 8)   // 1248 W1 A-frags (16x16x32)
#define SROW 136            // S_bf row stride in shorts (272B, 16B-aligned)
#define UGS  136            // Ub2 g-stride in shorts (272B: dw%32 = 4)
#define UFS  1096           // Ub2 f-stride in shorts (8*136+8; 2192B, 16B-aligned)

#define SBF_OFF   19968                        // xs = [0, 19968)
#define R_OFF     (SBF_OFF + 128 * SROW * 2)   // 54784: xTb / Ub2 region
#define XCH_OFF   (R_OFF + 16384)              // 71168: rowbufs then fp32 exchange
#define SMEM_SZ   (R_OFF + F0 * UFS * 2)       // 140272

typedef __attribute__((ext_vector_type(8)))  short    short8;
typedef __attribute__((ext_vector_type(8)))  _Float16 half8;
typedef __attribute__((ext_vector_type(2)))  _Float16 half2v;
typedef __attribute__((ext_vector_type(4)))  float    floatx4;
typedef __attribute__((ext_vector_type(16))) float    floatx16;

__device__ __forceinline__ unsigned short f16b(float f) {
  return __builtin_bit_cast(unsigned short, (_Float16)f);
}

__device__ __forceinline__ unsigned int pkrtz(float a, float b) {
  return __builtin_bit_cast(unsigned int, __builtin_amdgcn_cvt_pkrtz(a, b));
}

__device__ __forceinline__ floatx4 mfma16h(half8 a, half8 b, floatx4 c) {
  return __builtin_amdgcn_mfma_f32_16x16x32_f16(a, b, c, 0, 0, 0);
}

__device__ __forceinline__ floatx16 mfma32h(half8 a, half8 b, floatx16 c) {
  return __builtin_amdgcn_mfma_f32_32x32x16_f16(a, b, c, 0, 0, 0);
}

__device__ __forceinline__ half8 h8(short8 s) {
  return __builtin_bit_cast(half8, s);
}

// ================= cooperative fused kernel (pack + cin) =================
__global__ __launch_bounds__(1024, 4) void cin_coop(const float* __restrict__ x,
                                                    const float* __restrict__ w0,
                                                    const float* __restrict__ w1,
                                                    short8* __restrict__ wA1,
                                                    short8* __restrict__ wA2,
                                                    float* __restrict__ out) {
  // LDS: [0,19968) xs fp32 (reused as S32 in phase-3 reduce)
  //      [19968, +34816) S_bf (fp16)
  //      [54784, +16384) xTb (fp16, dies after phase-1 bq reads)
  //      [71168, ...) pack rowbufs (prologue) then Xch fp32 (phase-1)
  //      [54784, +85488) Ub2 (phase 2b/3; aliases xTb+Xch after barrier)
  __shared__ __align__(16) char smem[SMEM_SZ];
  float (*xs)[F0][D_]   = (float (*)[F0][D_])smem;
  float* S32            = (float*)smem;                       // phase 3 only
  unsigned short* S_bf  = (unsigned short*)(smem + SBF_OFF);  // [128][SROW]
  unsigned short* xTb   = (unsigned short*)(smem + R_OFF);
  unsigned short* Ub2   = xTb;                                // aliased
  float4*        Xch4   = (float4*)(smem + XCH_OFF);
  float*         rb0    = (float*)(smem + XCH_OFF);           // prologue only
  float*         rb1    = rb0 + 800;                          // prologue only

  const int tid  = threadIdx.x;
  const int lane = tid & 63;
  const int wv   = tid >> 6;      // 16 waves
  const int col  = lane & 15;
  const int quad = lane >> 4;
  const int b0   = blockIdx.x * G8;
  const floatx4 zf4 = {0.f, 0.f, 0.f, 0.f};

  // ---- pack slice coords: row pr of BOTH w0 and w1, f-half ph ----
  const int pr  = blockIdx.x >> 1;     // 0..127
  const int ph  = blockIdx.x & 1;
  const int fLo = ph ? 20 : 0;
  const int nfp = ph ? (F0 - 20) : 20; // 19 or 20

  // ---- stage x (coalesced float4) ----
  {
    const float4* xg = (const float4*)(x + (size_t)b0 * (F0 * D_));
    float4* xl = (float4*)smem;
    for (int i = tid; i < G8 * F0 * D_ / 4; i += 1024) xl[i] = xg[i];
  }
  // ---- stage W row-halves into rowbufs (coalesced dwords) ----
  {
    const float* s0 = w0 + (size_t)pr * P0_ + fLo * F0;
    const int c0 = nfp * F0;
    for (int i = tid; i < c0; i += 1024) rb0[i] = s0[i];
    const float* s1 = w1 + (size_t)pr * P1_ + fLo * 128;
    const int c1 = nfp * 128;
    for (int i = tid; i < c1; i += 1024) rb1[i] = s1[i];
  }
  __syncthreads();

  // ---- xTb[g][q8][d][j] = f16(x[g][q8*8+j][d]), zero-pad q>=39 ----
  {
    int i = tid;                      // exactly 1024 = G8*8*16 entries
    int d = i & 15, q8 = (i >> 4) & 7, g = i >> 7;
    union { short8 v; unsigned int u[4]; } pk;
#pragma unroll
    for (int jj = 0; jj < 4; ++jj) {
      int qa = q8 * 8 + jj * 2, qb = qa + 1;
      float va = (qa < F0) ? xs[g][qa][d] : 0.f;
      float vb = (qb < F0) ? xs[g][qb][d] : 0.f;
      pk.u[jj] = pkrtz(va, vb);
    }
    *(short8*)&xTb[(size_t)i * 8] = pk.v;
  }

  // ---- scatter-pack this block's W slice to d_ws ----
  // w0 items (threads [0, nfp*6)): frag=(f*3+ks)*4+(pr>>5), lane=kg*32+(pr&31)
  if (tid < nfp * 6) {
    int kg = tid & 1, ks = (tid >> 1) % 3, fl = tid / 6;
    int f  = fLo + fl;
    union { short8 v; unsigned int u[4]; } pk;
#pragma unroll
    for (int jj = 0; jj < 4; ++jj) {
      int q0 = ks * 16 + kg * 8 + jj * 2;
      float a = (q0     < F0) ? rb0[fl * F0 + q0]     : 0.f;
      float c = (q0 + 1 < F0) ? rb0[fl * F0 + q0 + 1] : 0.f;
      pk.u[jj] = pkrtz(a, c);
    }
    wA1[(size_t)((f * 3 + ks) * 4 + (pr >> 5)) * 64 + kg * 32 + (pr & 31)] = pk.v;
  }
  // w1 items (threads [512, 512+nfp*16)): frag=(f*4+s)*8+(pr>>4), lane=quad*16+(pr&15)
  if (tid >= 512 && tid < 512 + nfp * 16) {
    int it = tid - 512;
    int qd = it & 3, s = (it >> 2) & 3, fl = it >> 4;
    int f  = fLo + fl;
    const float* rp = &rb1[fl * 128 + s * 32 + qd * 8];
    union { short8 v; unsigned int u[4]; } pk;
#pragma unroll
    for (int jj = 0; jj < 4; ++jj) pk.u[jj] = pkrtz(rp[jj * 2], rp[jj * 2 + 1]);
    wA2[(size_t)((f * 4 + s) * 8 + (pr >> 4)) * 64 + qd * 16 + (pr & 15)] = pk.v;
  }

  // ---- publish pack, wait whole grid ----
  __threadfence();
  cg::this_grid().sync();

  // ---- phase-1 wave coords + 2-deep A-ring (post-sync: wA1 now valid) ----
  const int mt  = wv & 3;          // h-tile of 32
  const int gp2 = (wv >> 2) & 1;   // batch quad selector
  const int fh2 = wv >> 3;         // f-half
  const int fB  = fh2 ? 20 : 0;
  const int fE  = fh2 ? F0 : 20;

  short8 a0 = wA1[(size_t)((fB * 3 + 0) * 4 + mt) * 64 + lane];
  short8 a1 = wA1[(size_t)((fB * 3 + 1) * 4 + mt) * 64 + lane];
  short8 a2 = wA1[(size_t)((fB * 3 + 2) * 4 + mt) * 64 + lane];
  short8 p0 = wA1[(size_t)(((fB + 1) * 3 + 0) * 4 + mt) * 64 + lane];
  short8 p1 = wA1[(size_t)(((fB + 1) * 3 + 1) * 4 + mt) * 64 + lane];
  short8 p2 = wA1[(size_t)(((fB + 1) * 3 + 2) * 4 + mt) * 64 + lane];

  // ===== phase 1: 32x32x16 f16; wave = (fh2, gp2, mt). Two g-pair tiles =====
  {
    const int c32 = lane & 31;       // C col: n = g_local*16 + d
    const int kg  = lane >> 5;       // k half (8 q's each)
    const int d   = c32 & 15;
    const int gU  = gp2 * 4 + (c32 >> 4);
    const int gV  = gU + 2;

    half8 bu0 = h8(*(const short8*)&xTb[(size_t)(((gU * 8 + 0 + kg) * 16) + d) * 8]);
    half8 bu1 = h8(*(const short8*)&xTb[(size_t)(((gU * 8 + 2 + kg) * 16) + d) * 8]);
    half8 bu2 = h8(*(const short8*)&xTb[(size_t)(((gU * 8 + 4 + kg) * 16) + d) * 8]);
    half8 bv0 = h8(*(const short8*)&xTb[(size_t)(((gV * 8 + 0 + kg) * 16) + d) * 8]);
    half8 bv1 = h8(*(const short8*)&xTb[(size_t)(((gV * 8 + 2 + kg) * 16) + d) * 8]);
    half8 bv2 = h8(*(const short8*)&xTb[(size_t)(((gV * 8 + 4 + kg) * 16) + d) * 8]);

    floatx16 accU = {0.f, 0.f, 0.f, 0.f, 0.f, 0.f, 0.f, 0.f,
                     0.f, 0.f, 0.f, 0.f, 0.f, 0.f, 0.f, 0.f};
    floatx16 accV = accU;

    for (int f = fB; f < fE; ++f) {
      const int f2 = (f + 2 < fE) ? f + 2 : fE - 1;
      short8 n0 = wA1[(size_t)((f2 * 3 + 0) * 4 + mt) * 64 + lane];
      short8 n1 = wA1[(size_t)((f2 * 3 + 1) * 4 + mt) * 64 + lane];
      short8 n2 = wA1[(size_t)((f2 * 3 + 2) * 4 + mt) * 64 + lane];
      const _Float16 hU = (_Float16)xs[gU][f][d];
      const _Float16 hV = (_Float16)xs[gV][f][d];
      accU = mfma32h(h8(a0), bu0 * hU, accU);
      accV = mfma32h(h8(a0), bv0 * hV, accV);
      accU = mfma32h(h8(a1), bu1 * hU, accU);
      accV = mfma32h(h8(a1), bv1 * hV, accV);
      accU = mfma32h(h8(a2), bu2 * hU, accU);
      accV = mfma32h(h8(a2), bv2 * hV, accV);
      a0 = p0; a1 = p1; a2 = p2;
      p0 = n0; p1 = n1; p2 = n2;
    }

    // ---- f-half partial exchange (fp32 float4; rowbufs dead) ----
    const int wid = gp2 * 4 + mt;    // 0..7, shared by the fh2 pair
    if (fh2 == 0) {
#pragma unroll
      for (int seg = 0; seg < 4; ++seg) {
        float4 u4 = make_float4(accU[seg * 4 + 0], accU[seg * 4 + 1],
                                accU[seg * 4 + 2], accU[seg * 4 + 3]);
        Xch4[(size_t)((wid * 8 + seg) * 64) + lane] = u4;
        float4 v4 = make_float4(accV[seg * 4 + 0], accV[seg * 4 + 1],
                                accV[seg * 4 + 2], accV[seg * 4 + 3]);
        Xch4[(size_t)((wid * 8 + 4 + seg) * 64) + lane] = v4;
      }
    }
    __syncthreads();
    if (fh2 == 1) {
#pragma unroll
      for (int seg = 0; seg < 4; ++seg) {
        float4 u4 = Xch4[(size_t)((wid * 8 + seg) * 64) + lane];
        accU[seg * 4 + 0] += u4.x; accU[seg * 4 + 1] += u4.y;
        accU[seg * 4 + 2] += u4.z; accU[seg * 4 + 3] += u4.w;
        float4 v4 = Xch4[(size_t)((wid * 8 + 4 + seg) * 64) + lane];
        accV[seg * 4 + 0] += v4.x; accV[seg * 4 + 1] += v4.y;
        accV[seg * 4 + 2] += v4.z; accV[seg * 4 + 3] += v4.w;
      }
#pragma unroll
      for (int r = 0; r < 16; ++r) {
        const int row = (r & 3) + 8 * (r >> 2) + 4 * kg;
        S_bf[(size_t)(mt * 32 + row) * SROW + (gp2 * 2 + 0) * 32 + c32] = f16b(accU[r]);
        S_bf[(size_t)(mt * 32 + row) * SROW + (gp2 * 2 + 1) * 32 + c32] = f16b(accV[r]);
      }
    }
  }
  __syncthreads();

  // ===== phase 2a: out1[b,h] = sum_d h1 (1024 threads, one shot) =====
  {
    int h = tid & 127, g = tid >> 7;
    union { short8 v; unsigned int u[4]; } w0v, w1v;
    w0v.v = *(const short8*)&S_bf[(size_t)h * SROW + g * 16];
    w1v.v = *(const short8*)&S_bf[(size_t)h * SROW + g * 16 + 8];
    float sum = 0.f;
#pragma unroll
    for (int p = 0; p < 4; ++p) {
      half2v h0 = __builtin_bit_cast(half2v, w0v.u[p]);
      half2v h1 = __builtin_bit_cast(half2v, w1v.u[p]);
      sum += (float)h0[0] + (float)h0[1] + (float)h1[0] + (float)h1[1];
    }
    out[(size_t)(b0 + g) * 256 + h] = sum;
  }

  // ===== phase 2b: wave = (g, qh). U[g,(f,q)] = sum_d x[g,f,d] h1[g,q,d] =====
  {
    const int g  = wv & 7;
    const int qh = wv >> 3;
    short8 af[3];
#pragma unroll
    for (int ft = 0; ft < 3; ++ft) {
      union { short8 v; unsigned int u[4]; } pk;
      int f = ft * 16 + col;
      if (quad < 2 && f < F0) {
        const float4* xp = (const float4*)&xs[g][f][quad * 8];
        float4 x0 = xp[0], x1 = xp[1];
        pk.u[0] = pkrtz(x0.x, x0.y);
        pk.u[1] = pkrtz(x0.z, x0.w);
        pk.u[2] = pkrtz(x1.x, x1.y);
        pk.u[3] = pkrtz(x1.z, x1.w);
      } else {
        pk.u[0] = pk.u[1] = pk.u[2] = pk.u[3] = 0u;
      }
      af[ft] = pk.v;
    }
#pragma unroll
    for (int qi = 0; qi < 4; ++qi) {
      const int qt = qh * 4 + qi;
      short8 bq;
      if (quad < 2) {
        bq = *(const short8*)&S_bf[(size_t)(qt * 16 + col) * SROW + g * 16 + quad * 8];
      } else {
        bq = short8{0, 0, 0, 0, 0, 0, 0, 0};
      }
#pragma unroll
      for (int ft = 0; ft < 3; ++ft) {
        floatx4 c2 = mfma16h(h8(af[ft]), h8(bq), zf4);
        unsigned short* up =
            &Ub2[(size_t)(ft * 16 + quad * 4) * UFS + g * UGS + qt * 16 + col];
        if (ft < 2) {
#pragma unroll
          for (int r = 0; r < 4; ++r) up[r * UFS] = f16b(c2[r]);
        } else {
#pragma unroll
          for (int r = 0; r < 4; ++r)
            if (32 + quad * 4 + r < F0) up[r * UFS] = f16b(c2[r]);
        }
      }
    }
  }

  // ---- pre-issue phase-3's first W loads; 2b->3 barrier drain completes ----
  const int t3  = wv & 7;
  const int kh  = wv >> 3;
  const int cb0 = kh ? 20 : 0;
  const int cbN = kh ? F0 : 20;
  short8 aW[4], aX[4];
#pragma unroll
  for (int i = 0; i < 4; ++i)
    aW[i] = wA2[(size_t)((cb0 * 4 + i) * 8 + t3) * 64 + lane];
#pragma unroll
  for (int i = 0; i < 4; ++i)
    aX[i] = wA2[(size_t)(((cb0 + 1) * 4 + i) * 8 + t3) * 64 + lane];
  __syncthreads();

  // ===== phase 3: wave = (t, kh). out2 = sum_c W1frag(c) x Ufrag(c) =====
  {
    const short8 zero8 = {0, 0, 0, 0, 0, 0, 0, 0};
    floatx4 aco[4];
#pragma unroll
    for (int i = 0; i < 4; ++i) aco[i] = zf4;
    for (int cb = cb0; cb < cbN; ++cb) {
      const int c2i = (cb + 2 < cbN) ? cb + 2 : cbN - 1;
      short8 nx[4];
#pragma unroll
      for (int i = 0; i < 4; ++i)
        nx[i] = wA2[(size_t)((c2i * 4 + i) * 8 + t3) * 64 + lane];
      const unsigned short* ubase = &Ub2[(size_t)cb * UFS + col * UGS + quad * 8];
#pragma unroll
      for (int i = 0; i < 4; ++i) {
        short8 bU = (col < 8) ? *(const short8*)(ubase + i * 32) : zero8;
        aco[i] = mfma16h(h8(aW[i]), h8(bU), aco[i]);
      }
#pragma unroll
      for (int i = 0; i < 4; ++i) { aW[i] = aX[i]; aX[i] = nx[i]; }
    }
    float v[4];
#pragma unroll
    for (int r = 0; r < 4; ++r)
      v[r] = (aco[0][r] + aco[1][r]) + (aco[2][r] + aco[3][r]);

    if (kh == 0 && col < 8) {
#pragma unroll
      for (int r = 0; r < 4; ++r)
        S32[(size_t)(t3 * 16 + quad * 4 + r) * 9 + col] = v[r];
    }
    __syncthreads();
    if (kh == 1 && col < 8) {
#pragma unroll
      for (int r = 0; r < 4; ++r) {
        int h = t3 * 16 + quad * 4 + r;
        out[(size_t)(b0 + col) * 256 + 128 + h] = v[r] + S32[(size_t)h * 9 + col];
      }
    }
  }
}

// ================= classic fallback pair (R14, verbatim) =================
__global__ __launch_bounds__(256) void pack_w_kernel(const float* __restrict__ w0,
                                                     const float* __restrict__ w1,
                                                     short8* __restrict__ wA1,
                                                     short8* __restrict__ wA2) {
  __shared__ float row[P1_];
  const int tid = threadIdx.x;
  const int b   = blockIdx.x;
  if (b < H_) {
    const int m = b;
    const float* src = w0 + (size_t)m * P0_;
    for (int i = tid; i < P0_; i += 256) row[i] = src[i];
    __syncthreads();
    const int mt = m >> 5, lr = m & 31;
    for (int it = tid; it < F0 * 3 * 2; it += 256) {
      int kg = it & 1;
      int ks = (it >> 1) % 3;
      int f  = it / 6;
      int frag = (f * 3 + ks) * 4 + mt;
      int lane = kg * 32 + lr;
      union { short8 v; unsigned int u[4]; } pk;
#pragma unroll
      for (int jj = 0; jj < 4; ++jj) {
        int q0 = ks * 16 + kg * 8 + jj * 2;
        float a = (q0     < F0) ? row[f * F0 + q0]     : 0.f;
        float c = (q0 + 1 < F0) ? row[f * F0 + q0 + 1] : 0.f;
        pk.u[jj] = pkrtz(a, c);
      }
      wA1[(size_t)frag * 64 + lane] = pk.v;
    }
  } else {
    const int m = b - H_;
    const float4* src4 = (const float4*)(w1 + (size_t)m * P1_);
    float4* row4 = (float4*)row;
    for (int i = tid; i < P1_ / 4; i += 256) row4[i] = src4[i];
    __syncthreads();
    const int t = m >> 4, lc = m & 15;
    for (int it = tid; it < F0 * 16; it += 256) {
      int qd   = it & 3;
      int s    = (it >> 2) & 3;
      int f    = it >> 4;
      int frag = (f * 4 + s) * 8 + t;
      int lane = qd * 16 + lc;
      const float* rp = &row[f * 128 + s * 32 + qd * 8];
      union { short8 v; unsigned int u[4]; } pk;
#pragma unroll
      for (int jj = 0; jj < 4; ++jj) pk.u[jj] = pkrtz(rp[jj * 2], rp[jj * 2 + 1]);
      wA2[(size_t)frag * 64 + lane] = pk.v;
    }
  }
}

__global__ __launch_bounds__(1024, 4) void cin_fused(const float* __restrict__ x,
                                                     const short8* __restrict__ wA1,
                                                     const short8* __restrict__ wA2,
                                                     float* __restrict__ out) {
  __shared__ __align__(16) char smem[SMEM_SZ];
  float (*xs)[F0][D_]   = (float (*)[F0][D_])smem;
  float* S32            = (float*)smem;
  unsigned short* S_bf  = (unsigned short*)(smem + SBF_OFF);
  unsigned short* xTb   = (unsigned short*)(smem + R_OFF);
  unsigned short* Ub2   = xTb;
  float4*        Xch4   = (float4*)(smem + XCH_OFF);

  const int tid  = threadIdx.x;
  const int lane = tid & 63;
  const int wv   = tid >> 6;
  const int col  = lane & 15;
  const int quad = lane >> 4;
  const int b0   = blockIdx.x * G8;
  const floatx4 zf4 = {0.f, 0.f, 0.f, 0.f};

  const int mt  = wv & 3;
  const int gp2 = (wv >> 2) & 1;
  const int fh2 = wv >> 3;
  const int fB  = fh2 ? 20 : 0;
  const int fE  = fh2 ? F0 : 20;

  short8 a0 = wA1[(size_t)((fB * 3 + 0) * 4 + mt) * 64 + lane];
  short8 a1 = wA1[(size_t)((fB * 3 + 1) * 4 + mt) * 64 + lane];
  short8 a2 = wA1[(size_t)((fB * 3 + 2) * 4 + mt) * 64 + lane];
  short8 p0 = wA1[(size_t)(((fB + 1) * 3 + 0) * 4 + mt) * 64 + lane];
  short8 p1 = wA1[(size_t)(((fB + 1) * 3 + 1) * 4 + mt) * 64 + lane];
  short8 p2 = wA1[(size_t)(((fB + 1) * 3 + 2) * 4 + mt) * 64 + lane];

  {
    const float4* xg = (const float4*)(x + (size_t)b0 * (F0 * D_));
    float4* xl = (float4*)smem;
    for (int i = tid; i < G8 * F0 * D_ / 4; i += 1024) xl[i] = xg[i];
  }
  __syncthreads();

  {
    int i = tid;
    int d = i & 15, q8 = (i >> 4) & 7, g = i >> 7;
    union { short8 v; unsigned int u[4]; } pk;
#pragma unroll
    for (int jj = 0; jj < 4; ++jj) {
      int qa = q8 * 8 + jj * 2, qb = qa + 1;
      float va = (qa < F0) ? xs[g][qa][d] : 0.f;
      float vb = (qb < F0) ? xs[g][qb][d] : 0.f;
      pk.u[jj] = pkrtz(va, vb);
    }
    *(short8*)&xTb[(size_t)i * 8] = pk.v;
  }
  __syncthreads();

  {
    const int c32 = lane & 31;
    const int kg  = lane >> 5;
    const int d   = c32 & 15;
    const int gU  = gp2 * 4 + (c32 >> 4);
    const int gV  = gU + 2;

    half8 bu0 = h8(*(const short8*)&xTb[(size_t)(((gU * 8 + 0 + kg) * 16) + d) * 8]);
    half8 bu1 = h8(*(const short8*)&xTb[(size_t)(((gU * 8 + 2 + kg) * 16) + d) * 8]);
    half8 bu2 = h8(*(const short8*)&xTb[(size_t)(((gU * 8 + 4 + kg) * 16) + d) * 8]);
    half8 bv0 = h8(*(const short8*)&xTb[(size_t)(((gV * 8 + 0 + kg) * 16) + d) * 8]);
    half8 bv1 = h8(*(const short8*)&xTb[(size_t)(((gV * 8 + 2 + kg) * 16) + d) * 8]);
    half8 bv2 = h8(*(const short8*)&xTb[(size_t)(((gV * 8 + 4 + kg) * 16) + d) * 8]);

    floatx16 accU = {0.f, 0.f, 0.f, 0.f, 0.f, 0.f, 0.f, 0.f,
                     0.f, 0.f, 0.f, 0.f, 0.f, 0.f, 0.f, 0.f};
    floatx16 accV = accU;

    for (int f = fB; f < fE; ++f) {
      const int f2 = (f + 2 < fE) ? f + 2 : fE - 1;
      short8 n0 = wA1[(size_t)((f2 * 3 + 0) * 4 + mt) * 64 + lane];
      short8 n1 = wA1[(size_t)((f2 * 3 + 1) * 4 + mt) * 64 + lane];
      short8 n2 = wA1[(size_t)((f2 * 3 + 2) * 4 + mt) * 64 + lane];
      const _Float16 hU = (_Float16)xs[gU][f][d];
      const _Float16 hV = (_Float16)xs[gV][f][d];
      accU = mfma32h(h8(a0), bu0 * hU, accU);
      accV = mfma32h(h8(a0), bv0 * hV, accV);
      accU = mfma32h(h8(a1), bu1 * hU, accU);
      accV = mfma32h(h8(a1), bv1 * hV, accV);
      accU = mfma32h(h8(a2), bu2 * hU, accU);
      accV = mfma32h(h8(a2), bv2 * hV, accV);
      a0 = p0; a1 = p1; a2 = p2;
      p0 = n0; p1 = n1; p2 = n2;
    }

    const int wid = gp2 * 4 + mt;
    if (fh2 == 0) {
#pragma unroll
      for (int seg = 0; seg < 4; ++seg) {
        float4 u4 = make_float4(accU[seg * 4 + 0], accU[seg * 4 + 1],
                                accU[seg * 4 + 2], accU[seg * 4 + 3]);
        Xch4[(size_t)((wid * 8 + seg) * 64) + lane] = u4;
        float4 v4 = make_float4(accV[seg * 4 + 0], accV[seg * 4 + 1],
                                accV[seg * 4 + 2], accV[seg * 4 + 3]);
        Xch4[(size_t)((wid * 8 + 4 + seg) * 64) + lane] = v4;
      }
    }
    __syncthreads();
    if (fh2 == 1) {
#pragma unroll
      for (int seg = 0; seg < 4; ++seg) {
        float4 u4 = Xch4[(size_t)((wid * 8 + seg) * 64) + lane];
        accU[seg * 4 + 0] += u4.x; accU[seg * 4 + 1] += u4.y;
        accU[seg * 4 + 2] += u4.z; accU[seg * 4 + 3] += u4.w;
        float4 v4 = Xch4[(size_t)((wid * 8 + 4 + seg) * 64) + lane];
        accV[seg * 4 + 0] += v4.x; accV[seg * 4 + 1] += v4.y;
        accV[seg * 4 + 2] += v4.z; accV[seg * 4 + 3] += v4.w;
      }
#pragma unroll
      for (int r = 0; r < 16; ++r) {
        const int row = (r & 3) + 8 * (r >> 2) + 4 * kg;
        S_bf[(size_t)(mt * 32 + row) * SROW + (gp2 * 2 + 0) * 32 + c32] = f16b(accU[r]);
        S_bf[(size_t)(mt * 32 + row) * SROW + (gp2 * 2 + 1) * 32 + c32] = f16b(accV[r]);
      }
    }
  }
  __syncthreads();

  {
    int h = tid & 127, g = tid >> 7;
    union { short8 v; unsigned int u[4]; } w0v, w1v;
    w0v.v = *(const short8*)&S_bf[(size_t)h * SROW + g * 16];
    w1v.v = *(const short8*)&S_bf[(size_t)h * SROW + g * 16 + 8];
    float sum = 0.f;
#pragma unroll
    for (int p = 0; p < 4; ++p) {
      half2v h0 = __builtin_bit_cast(half2v, w0v.u[p]);
      half2v h1 = __builtin_bit_cast(half2v, w1v.u[p]);
      sum += (float)h0[0] + (float)h0[1] + (float)h1[0] + (float)h1[1];
    }
    out[(size_t)(b0 + g) * 256 + h] = sum;
  }

  {
    const int g  = wv & 7;
    const int qh = wv >> 3;
    short8 af[3];
#pragma unroll
    for (int ft = 0; ft < 3; ++ft) {
      union { short8 v; unsigned int u[4]; } pk;
      int f = ft * 16 + col;
      if (quad < 2 && f < F0) {
        const float4* xp = (const float4*)&xs[g][f][quad * 8];
        float4 x0 = xp[0], x1 = xp[1];
        pk.u[0] = pkrtz(x0.x, x0.y);
        pk.u[1] = pkrtz(x0.z, x0.w);
        pk.u[2] = pkrtz(x1.x, x1.y);
        pk.u[3] = pkrtz(x1.z, x1.w);
      } else {
        pk.u[0] = pk.u[1] = pk.u[2] = pk.u[3] = 0u;
      }
      af[ft] = pk.v;
    }
#pragma unroll
    for (int qi = 0; qi < 4; ++qi) {
      const int qt = qh * 4 + qi;
      short8 bq;
      if (quad < 2) {
        bq = *(const short8*)&S_bf[(size_t)(qt * 16 + col) * SROW + g * 16 + quad * 8];
      } else {
        bq = short8{0, 0, 0, 0, 0, 0, 0, 0};
      }
#pragma unroll
      for (int ft = 0; ft < 3; ++ft) {
        floatx4 c2 = mfma16h(h8(af[ft]), h8(bq), zf4);
        unsigned short* up =
            &Ub2[(size_t)(ft * 16 + quad * 4) * UFS + g * UGS + qt * 16 + col];
        if (ft < 2) {
#pragma unroll
          for (int r = 0; r < 4; ++r) up[r * UFS] = f16b(c2[r]);
        } else {
#pragma unroll
          for (int r = 0; r < 4; ++r)
            if (32 + quad * 4 + r < F0) up[r * UFS] = f16b(c2[r]);
        }
      }
    }
  }

  const int t3  = wv & 7;
  const int kh  = wv >> 3;
  const int cb0 = kh ? 20 : 0;
  const int cbN = kh ? F0 : 20;
  short8 aW[4], aX[4];
#pragma unroll
  for (int i = 0; i < 4; ++i)
    aW[i] = wA2[(size_t)((cb0 * 4 + i) * 8 + t3) * 64 + lane];
#pragma unroll
  for (int i = 0; i < 4; ++i)
    aX[i] = wA2[(size_t)(((cb0 + 1) * 4 + i) * 8 + t3) * 64 + lane];
  __syncthreads();

  {
    const short8 zero8 = {0, 0, 0, 0, 0, 0, 0, 0};
    floatx4 aco[4];
#pragma unroll
    for (int i = 0; i < 4; ++i) aco[i] = zf4;
    for (int cb = cb0; cb < cbN; ++cb) {
      const int c2i = (cb + 2 < cbN) ? cb + 2 : cbN - 1;
      short8 nx[4];
#pragma unroll
      for (int i = 0; i < 4; ++i)
        nx[i] = wA2[(size_t)((c2i * 4 + i) * 8 + t3) * 64 + lane];
      const unsigned short* ubase = &Ub2[(size_t)cb * UFS + col * UGS + quad * 8];
#pragma unroll
      for (int i = 0; i < 4; ++i) {
        short8 bU = (col < 8) ? *(const short8*)(ubase + i * 32) : zero8;
        aco[i] = mfma16h(h8(aW[i]), h8(bU), aco[i]);
      }
#pragma unroll
      for (int i = 0; i < 4; ++i) { aW[i] = aX[i]; aX[i] = nx[i]; }
    }
    float v[4];
#pragma unroll
    for (int r = 0; r < 4; ++r)
      v[r] = (aco[0][r] + aco[1][r]) + (aco[2][r] + aco[3][r]);

    if (kh == 0 && col < 8) {
#pragma unroll
      for (int r = 0; r < 4; ++r)
        S32[(size_t)(t3 * 16 + quad * 4 + r) * 9 + col] = v[r];
    }
    __syncthreads();
    if (kh == 1 && col < 8) {
#pragma unroll
      for (int r = 0; r < 4; ++r) {
        int h = t3 * 16 + quad * 4 + r;
        out[(size_t)(b0 + col) * 256 + 128 + h] = v[r] + S32[(size_t)h * 9 + col];
      }
    }
  }
}

// ---------- fp32 last-resort fallback ----------
__global__ __launch_bounds__(128) void cin_fused_fallback(const float* __restrict__ x,
                                                          const float* __restrict__ w0,
                                                          const float* __restrict__ w1,
                                                          float* __restrict__ out) {
  __shared__ float4 xs4[F0 * D_ / 4];
  __shared__ float4 h1s4[H_ * D_ / 4];
  __shared__ float4 z4[H_ * D_ / 4];
  const int tid = threadIdx.x;
  const int b = blockIdx.x;
  const int hh = tid >> 2, dd = tid & 3, h0 = hh << 2;
  {
    const float4* xg = (const float4*)(x + (size_t)b * (F0 * D_));
    for (int i = tid; i < F0 * D_ / 4; i += 128) xs4[i] = xg[i];
  }
  __syncthreads();
  float acc[4][4];
#pragma unroll
  for (int i = 0; i < 4; ++i)
#pragma unroll
    for (int j = 0; j < 4; ++j) acc[i][j] = 0.f;
  for (int f = 0; f < F0; ++f) {
    for (int i = tid; i < F0 * D_ / 4; i += 128) {
      float4 xv = xs4[(f << 2) + (i & 3)], qv = xs4[i];
      z4[i] = make_float4(xv.x * qv.x, xv.y * qv.y, xv.z * qv.z, xv.w * qv.w);
    }
    __syncthreads();
    for (int q = 0; q < F0; ++q) {
      float4 zv = z4[(q << 2) + dd];
      int p = f * F0 + q;
      float ww[4] = {w0[(h0 + 0) * P0_ + p], w0[(h0 + 1) * P0_ + p],
                     w0[(h0 + 2) * P0_ + p], w0[(h0 + 3) * P0_ + p]};
      float zz[4] = {zv.x, zv.y, zv.z, zv.w};
#pragma unroll
      for (int hi = 0; hi < 4; ++hi)
#pragma unroll
        for (int di = 0; di < 4; ++di) acc[hi][di] += ww[hi] * zz[di];
    }
    __syncthreads();
  }
#pragma unroll
  for (int hi = 0; hi < 4; ++hi)
    h1s4[(h0 + hi) * 4 + dd] = make_float4(acc[hi][0], acc[hi][1], acc[hi][2], acc[hi][3]);
  __syncthreads();
  {
    float4 a0 = h1s4[tid * 4 + 0], a1 = h1s4[tid * 4 + 1];
    float4 a2 = h1s4[tid * 4 + 2], a3 = h1s4[tid * 4 + 3];
    out[(size_t)b * 256 + tid] = (a0.x + a0.y + a0.z + a0.w) + (a1.x + a1.y + a1.z + a1.w) +
                                 (a2.x + a2.y + a2.z + a2.w) + (a3.x + a3.y + a3.z + a3.w);
  }
#pragma unroll
  for (int i = 0; i < 4; ++i)
#pragma unroll
    for (int j = 0; j < 4; ++j) acc[i][j] = 0.f;
  for (int f = 0; f < F0; ++f) {
    for (int i = tid; i < H_ * D_ / 4; i += 128) {
      float4 xv = xs4[(f << 2) + (i & 3)], hv = h1s4[i];
      z4[i] = make_float4(xv.x * hv.x, xv.y * hv.y, xv.z * hv.z, xv.w * hv.w);
    }
    __syncthreads();
    for (int q = 0; q < H_; ++q) {
      float4 zv = z4[(q << 2) + dd];
      int p = f * H_ + q;
      float ww[4] = {w1[(h0 + 0) * P1_ + p], w1[(h0 + 1) * P1_ + p],
                     w1[(h0 + 2) * P1_ + p], w1[(h0 + 3) * P1_ + p]};
      float zz[4] = {zv.x, zv.y, zv.z, zv.w};
#pragma unroll
      for (int hi = 0; hi < 4; ++hi)
#pragma unroll
        for (int di = 0; di < 4; ++di) acc[hi][di] += ww[hi] * zz[di];
    }
    __syncthreads();
  }
#pragma unroll
  for (int hi = 0; hi < 4; ++hi)
    z4[(h0 + hi) * 4 + dd] = make_float4(acc[hi][0], acc[hi][1], acc[hi][2], acc[hi][3]);
  __syncthreads();
  {
    float4 a0 = z4[tid * 4 + 0], a1 = z4[tid * 4 + 1];
    float4 a2 = z4[tid * 4 + 2], a3 = z4[tid * 4 + 3];
    out[(size_t)b * 256 + 128 + tid] = (a0.x + a0.y + a0.z + a0.w) + (a1.x + a1.y + a1.z + a1.w) +
                                       (a2.x + a2.y + a2.z + a2.w) + (a3.x + a3.y + a3.z + a3.w);
  }
}

extern "C" void kernel_launch(void* const* d_in, const int* in_sizes, int n_in,
                              void* d_out, int out_size, void* d_ws, size_t ws_size,
                              hipStream_t stream) {
  const float* x  = (const float*)d_in[0];
  const float* w0 = (const float*)d_in[1];
  const float* w1 = (const float*)d_in[2];
  float* out = (float*)d_out;

  const size_t nfr    = (size_t)(NF1 + NF2) * 64;   // 109824 (frag,lane) pairs
  const size_t wbytes = nfr * sizeof(short8);       // ~1.76 MB

  if (ws_size >= wbytes) {
    short8* wA1 = (short8*)d_ws;
    short8* wA2 = wA1 + (size_t)NF1 * 64;
    void* args[] = {(void*)&x, (void*)&w0, (void*)&w1,
                    (void*)&wA1, (void*)&wA2, (void*)&out};
    hipError_t e = hipLaunchCooperativeKernel((const void*)cin_coop, dim3(256),
                                              dim3(1024), args, 0, stream);
    if (e != hipSuccess) {
      (void)hipGetLastError();   // clear error state, fall back to classic pair
      pack_w_kernel<<<256, 256, 0, stream>>>(w0, w1, wA1, wA2);
      cin_fused<<<256, 1024, 0, stream>>>(x, wA1, wA2, out);
    }
  } else {
    cin_fused_fallback<<<2048, 128, 0, stream>>>(x, w0, w1, out);
  }
}

// Round 9
// 96.325 us; speedup vs baseline: 2.3783x; 2.3783x over previous
//
#include <hip/hip_runtime.h>

// CIN fully fused, d-contraction-first. R16 = R14 (best, 94.9us: coalesced
// pack + R12 cin) + ring-depth isolation: phase-1 A-ring 3-deep + sx
// one-ahead prefetch (phase-local registers), phase-3 W-ring 3-deep issued
// ONLY at the pre-barrier point (48 VGPR across the barrier, not across
// 2b's body — R13's suspected spill source stays out). R15's coop
// grid.sync measured at ~110us overhead -> reverted permanently.
//   out1[b,h] = sum_d h1[b,h,d];  h1 = sum_{f,q} W0[h,fq] x[b,f,d] x[b,q,d]
//   out2[b,h] = sum_p W1[h,p] U[b,p];  U[b,(f,q)] = sum_d x[b,f,d] h1[b,q,d]
// 256 blocks x 1024 thr, 1 block/CU, ~140KB LDS, fp16 datapath.

#define F0   39
#define D_   16
#define H_   128
#define P0_  1521
#define P1_  4992
#define G8   8
#define NF1  (F0 * 3 * 4)   // 468 layer-1 A-frags (f x ks x mt), 32x32x16
#define NF2  (F0 * 4 * 8)   // 1248 W1 A-frags (16x16x32)
#define SROW 136            // S_bf row stride in shorts (272B, 16B-aligned)
#define UGS  136            // Ub2 g-stride in shorts (272B: dw%32 = 4)
#define UFS  1096           // Ub2 f-stride in shorts (8*136+8; 2192B, 16B-aligned)

#define SBF_OFF   19968                        // xs = [0, 19968)
#define R_OFF     (SBF_OFF + 128 * SROW * 2)   // 54784: xTb / Ub2 region
#define XCH_OFF   (R_OFF + 16384)              // 71168: fp32 exchange (64KB)
#define SMEM_SZ   (R_OFF + F0 * UFS * 2)       // 140272

typedef __attribute__((ext_vector_type(8)))  short    short8;
typedef __attribute__((ext_vector_type(8)))  _Float16 half8;
typedef __attribute__((ext_vector_type(2)))  _Float16 half2v;
typedef __attribute__((ext_vector_type(4)))  float    floatx4;
typedef __attribute__((ext_vector_type(16))) float    floatx16;

__device__ __forceinline__ unsigned short f16b(float f) {
  return __builtin_bit_cast(unsigned short, (_Float16)f);
}

__device__ __forceinline__ unsigned int pkrtz(float a, float b) {
  return __builtin_bit_cast(unsigned int, __builtin_amdgcn_cvt_pkrtz(a, b));
}

__device__ __forceinline__ floatx4 mfma16h(half8 a, half8 b, floatx4 c) {
  return __builtin_amdgcn_mfma_f32_16x16x32_f16(a, b, c, 0, 0, 0);
}

__device__ __forceinline__ floatx16 mfma32h(half8 a, half8 b, floatx16 c) {
  return __builtin_amdgcn_mfma_f32_32x32x16_f16(a, b, c, 0, 0, 0);
}

__device__ __forceinline__ half8 h8(short8 s) {
  return __builtin_bit_cast(half8, s);
}

// ---------- pack W into MFMA A-frag order: one block per W row ----------
// wA1 (32x32x16): frag = (f*3 + ks)*4 + mt
//   A[m][k]: m = mt*32 + (lane&31), k = (lane>>5)*8 + j, q = ks*16 + k
//   -> row m supplies (f, ks, kg): frag=(f*3+ks)*4+(m>>5), lane=kg*32+(m&31)
// wA2 (16x16x32): frag = (f*4 + s)*8 + t, m = t*16+(lane&15)
//   -> row m supplies (f, s, quad): frag=(f*4+s)*8+(m>>4), lane=quad*16+(m&15)
__global__ __launch_bounds__(256) void pack_w_kernel(const float* __restrict__ w0,
                                                     const float* __restrict__ w1,
                                                     short8* __restrict__ wA1,
                                                     short8* __restrict__ wA2) {
  __shared__ float row[P1_];          // 19968B max
  const int tid = threadIdx.x;
  const int b   = blockIdx.x;
  if (b < H_) {
    const int m = b;
    const float* src = w0 + (size_t)m * P0_;
    for (int i = tid; i < P0_; i += 256) row[i] = src[i];   // coalesced dwords
    __syncthreads();
    const int mt = m >> 5, lr = m & 31;
    for (int it = tid; it < F0 * 3 * 2; it += 256) {        // 234 items
      int kg = it & 1;
      int ks = (it >> 1) % 3;
      int f  = it / 6;
      int frag = (f * 3 + ks) * 4 + mt;
      int lane = kg * 32 + lr;
      union { short8 v; unsigned int u[4]; } pk;
#pragma unroll
      for (int jj = 0; jj < 4; ++jj) {
        int q0 = ks * 16 + kg * 8 + jj * 2;
        float a = (q0     < F0) ? row[f * F0 + q0]     : 0.f;
        float c = (q0 + 1 < F0) ? row[f * F0 + q0 + 1] : 0.f;
        pk.u[jj] = pkrtz(a, c);
      }
      wA1[(size_t)frag * 64 + lane] = pk.v;
    }
  } else {
    const int m = b - H_;
    const float4* src4 = (const float4*)(w1 + (size_t)m * P1_);  // 19968B row
    float4* row4 = (float4*)row;
    for (int i = tid; i < P1_ / 4; i += 256) row4[i] = src4[i];  // coalesced float4
    __syncthreads();
    const int t = m >> 4, lc = m & 15;
    for (int it = tid; it < F0 * 16; it += 256) {           // 624 items
      int quad = it & 3;
      int s    = (it >> 2) & 3;
      int f    = it >> 4;
      int frag = (f * 4 + s) * 8 + t;
      int lane = quad * 16 + lc;
      const float* rp = &row[f * 128 + s * 32 + quad * 8];
      union { short8 v; unsigned int u[4]; } pk;
#pragma unroll
      for (int jj = 0; jj < 4; ++jj) pk.u[jj] = pkrtz(rp[jj * 2], rp[jj * 2 + 1]);
      wA2[(size_t)frag * 64 + lane] = pk.v;
    }
  }
}

// ---------- fused main kernel ----------
__global__ __launch_bounds__(1024, 4) void cin_fused(const float* __restrict__ x,
                                                     const short8* __restrict__ wA1,
                                                     const short8* __restrict__ wA2,
                                                     float* __restrict__ out) {
  // LDS: [0,19968) xs fp32 (reused as S32 in phase-3 reduce)
  //      [19968, +34816) S_bf (fp16)
  //      [54784, +16384) xTb (fp16, dies after phase-1 bq reads)
  //      [71168, +65536) Xch fp32 (phase-1 partial exchange)
  //      [54784, +85488) Ub2 (phase 2b/3; aliases xTb+Xch after barrier)
  __shared__ __align__(16) char smem[SMEM_SZ];
  float (*xs)[F0][D_]   = (float (*)[F0][D_])smem;
  float* S32            = (float*)smem;                       // phase 3 only
  unsigned short* S_bf  = (unsigned short*)(smem + SBF_OFF);  // [128][SROW]
  unsigned short* xTb   = (unsigned short*)(smem + R_OFF);
  unsigned short* Ub2   = xTb;                                // aliased
  float4*        Xch4   = (float4*)(smem + XCH_OFF);

  const int tid  = threadIdx.x;
  const int lane = tid & 63;
  const int wv   = tid >> 6;      // 16 waves
  const int col  = lane & 15;
  const int quad = lane >> 4;
  const int b0   = blockIdx.x * G8;
  const floatx4 zf4 = {0.f, 0.f, 0.f, 0.f};

  // ---- phase-1 wave coords (early, for top-of-kernel A prefetch) ----
  const int mt  = wv & 3;          // h-tile of 32
  const int gp2 = (wv >> 2) & 1;   // batch quad selector
  const int fh2 = wv >> 3;         // f-half
  const int fB  = fh2 ? 20 : 0;
  const int fE  = fh2 ? F0 : 20;

  // 3-deep A-ring; first slots issue now, latency hides under x staging
  short8 a0 = wA1[(size_t)(((fB + 0) * 3 + 0) * 4 + mt) * 64 + lane];
  short8 a1 = wA1[(size_t)(((fB + 0) * 3 + 1) * 4 + mt) * 64 + lane];
  short8 a2 = wA1[(size_t)(((fB + 0) * 3 + 2) * 4 + mt) * 64 + lane];
  short8 p0 = wA1[(size_t)(((fB + 1) * 3 + 0) * 4 + mt) * 64 + lane];
  short8 p1 = wA1[(size_t)(((fB + 1) * 3 + 1) * 4 + mt) * 64 + lane];
  short8 p2 = wA1[(size_t)(((fB + 1) * 3 + 2) * 4 + mt) * 64 + lane];
  short8 q0r = wA1[(size_t)(((fB + 2) * 3 + 0) * 4 + mt) * 64 + lane];
  short8 q1r = wA1[(size_t)(((fB + 2) * 3 + 1) * 4 + mt) * 64 + lane];
  short8 q2r = wA1[(size_t)(((fB + 2) * 3 + 2) * 4 + mt) * 64 + lane];

  // ---- stage x (coalesced float4) ----
  {
    const float4* xg = (const float4*)(x + (size_t)b0 * (F0 * D_));
    float4* xl = (float4*)smem;
    for (int i = tid; i < G8 * F0 * D_ / 4; i += 1024) xl[i] = xg[i];
  }
  __syncthreads();

  // ---- xTb[g][q8][d][j] = f16(x[g][q8*8+j][d]), zero-pad q>=39 ----
  {
    int i = tid;                      // exactly 1024 = G8*8*16 entries
    int d = i & 15, q8 = (i >> 4) & 7, g = i >> 7;
    union { short8 v; unsigned int u[4]; } pk;
#pragma unroll
    for (int jj = 0; jj < 4; ++jj) {
      int qa = q8 * 8 + jj * 2, qb = qa + 1;
      float va = (qa < F0) ? xs[g][qa][d] : 0.f;
      float vb = (qb < F0) ? xs[g][qb][d] : 0.f;
      pk.u[jj] = pkrtz(va, vb);
    }
    *(short8*)&xTb[(size_t)i * 8] = pk.v;
  }
  __syncthreads();

  // ===== phase 1: 32x32x16 f16; wave = (fh2, gp2, mt). Two g-pair tiles =====
  // per f: acc = mfma(W0frag, bq * f16(x[g,f,d]), acc) x3 — scale folded
  // into B via v_pk_mul_f16, MFMA accumulates directly.
  {
    const int c32 = lane & 31;       // C col: n = g_local*16 + d
    const int kg  = lane >> 5;       // k half (8 q's each)
    const int d   = c32 & 15;
    const int gU  = gp2 * 4 + (c32 >> 4);
    const int gV  = gU + 2;

    // B[n][k]: n = c32, k = kg*8+j, q = ks*16 + k  ->  xTb[g][ks*2+kg][d][j]
    half8 bu0 = h8(*(const short8*)&xTb[(size_t)(((gU * 8 + 0 + kg) * 16) + d) * 8]);
    half8 bu1 = h8(*(const short8*)&xTb[(size_t)(((gU * 8 + 2 + kg) * 16) + d) * 8]);
    half8 bu2 = h8(*(const short8*)&xTb[(size_t)(((gU * 8 + 4 + kg) * 16) + d) * 8]);
    half8 bv0 = h8(*(const short8*)&xTb[(size_t)(((gV * 8 + 0 + kg) * 16) + d) * 8]);
    half8 bv1 = h8(*(const short8*)&xTb[(size_t)(((gV * 8 + 2 + kg) * 16) + d) * 8]);
    half8 bv2 = h8(*(const short8*)&xTb[(size_t)(((gV * 8 + 4 + kg) * 16) + d) * 8]);

    floatx16 accU = {0.f, 0.f, 0.f, 0.f, 0.f, 0.f, 0.f, 0.f,
                     0.f, 0.f, 0.f, 0.f, 0.f, 0.f, 0.f, 0.f};
    floatx16 accV = accU;

    float sxU = xs[gU][fB][d];
    float sxV = xs[gV][fB][d];
    for (int f = fB; f < fE; ++f) {
      const int f3 = (f + 3 < fE) ? f + 3 : fE - 1;
      const int f1 = (f + 1 < fE) ? f + 1 : fE - 1;
      short8 n0 = wA1[(size_t)((f3 * 3 + 0) * 4 + mt) * 64 + lane];
      short8 n1 = wA1[(size_t)((f3 * 3 + 1) * 4 + mt) * 64 + lane];
      short8 n2 = wA1[(size_t)((f3 * 3 + 2) * 4 + mt) * 64 + lane];
      const float nsxU = xs[gU][f1][d];
      const float nsxV = xs[gV][f1][d];
      const _Float16 hU = (_Float16)sxU;
      const _Float16 hV = (_Float16)sxV;
      accU = mfma32h(h8(a0), bu0 * hU, accU);
      accV = mfma32h(h8(a0), bv0 * hV, accV);
      accU = mfma32h(h8(a1), bu1 * hU, accU);
      accV = mfma32h(h8(a1), bv1 * hV, accV);
      accU = mfma32h(h8(a2), bu2 * hU, accU);
      accV = mfma32h(h8(a2), bv2 * hV, accV);
      a0 = p0; a1 = p1; a2 = p2;
      p0 = q0r; p1 = q1r; p2 = q2r;
      q0r = n0; q1r = n1; q2r = n2;
      sxU = nsxU; sxV = nsxV;
    }

    // ---- f-half partial exchange (fp32 float4, conflict-free) ----
    const int wid = gp2 * 4 + mt;    // 0..7, shared by the fh2 pair
    if (fh2 == 0) {
#pragma unroll
      for (int seg = 0; seg < 4; ++seg) {
        float4 u4 = make_float4(accU[seg * 4 + 0], accU[seg * 4 + 1],
                                accU[seg * 4 + 2], accU[seg * 4 + 3]);
        Xch4[(size_t)((wid * 8 + seg) * 64) + lane] = u4;
        float4 v4 = make_float4(accV[seg * 4 + 0], accV[seg * 4 + 1],
                                accV[seg * 4 + 2], accV[seg * 4 + 3]);
        Xch4[(size_t)((wid * 8 + 4 + seg) * 64) + lane] = v4;
      }
    }
    __syncthreads();
    if (fh2 == 1) {
#pragma unroll
      for (int seg = 0; seg < 4; ++seg) {
        float4 u4 = Xch4[(size_t)((wid * 8 + seg) * 64) + lane];
        accU[seg * 4 + 0] += u4.x; accU[seg * 4 + 1] += u4.y;
        accU[seg * 4 + 2] += u4.z; accU[seg * 4 + 3] += u4.w;
        float4 v4 = Xch4[(size_t)((wid * 8 + 4 + seg) * 64) + lane];
        accV[seg * 4 + 0] += v4.x; accV[seg * 4 + 1] += v4.y;
        accV[seg * 4 + 2] += v4.z; accV[seg * 4 + 3] += v4.w;
      }
      // final h1 -> S_bf (f16). Row = mt*32 + ((r&3)+8*(r>>2)+4*kg).
#pragma unroll
      for (int r = 0; r < 16; ++r) {
        const int row = (r & 3) + 8 * (r >> 2) + 4 * kg;
        S_bf[(size_t)(mt * 32 + row) * SROW + (gp2 * 2 + 0) * 32 + c32] = f16b(accU[r]);
        S_bf[(size_t)(mt * 32 + row) * SROW + (gp2 * 2 + 1) * 32 + c32] = f16b(accV[r]);
      }
    }
  }
  __syncthreads();

  // ===== phase 2a: out1[b,h] = sum_d h1 (1024 threads, one shot) =====
  {
    int h = tid & 127, g = tid >> 7;
    union { short8 v; unsigned int u[4]; } w0v, w1v;
    w0v.v = *(const short8*)&S_bf[(size_t)h * SROW + g * 16];
    w1v.v = *(const short8*)&S_bf[(size_t)h * SROW + g * 16 + 8];
    float sum = 0.f;
#pragma unroll
    for (int p = 0; p < 4; ++p) {
      half2v h0 = __builtin_bit_cast(half2v, w0v.u[p]);
      half2v h1 = __builtin_bit_cast(half2v, w1v.u[p]);
      sum += (float)h0[0] + (float)h0[1] + (float)h1[0] + (float)h1[1];
    }
    out[(size_t)(b0 + g) * 256 + h] = sum;
  }

  // ===== phase 2b: wave = (g, qh). U[g,(f,q)] = sum_d x[g,f,d] h1[g,q,d] =====
  // MFMA: A[m=f][k=d], B[n=q][k=d] -> C[m=f][n=q].
  // Store to Ub2[f][g][q] (f16): imm-offset b16 stores, <=2-way banks.
  {
    const int g  = wv & 7;
    const int qh = wv >> 3;
    short8 af[3];
#pragma unroll
    for (int ft = 0; ft < 3; ++ft) {
      union { short8 v; unsigned int u[4]; } pk;
      int f = ft * 16 + col;
      if (quad < 2 && f < F0) {
        const float4* xp = (const float4*)&xs[g][f][quad * 8];
        float4 x0 = xp[0], x1 = xp[1];
        pk.u[0] = pkrtz(x0.x, x0.y);
        pk.u[1] = pkrtz(x0.z, x0.w);
        pk.u[2] = pkrtz(x1.x, x1.y);
        pk.u[3] = pkrtz(x1.z, x1.w);
      } else {
        pk.u[0] = pk.u[1] = pk.u[2] = pk.u[3] = 0u;
      }
      af[ft] = pk.v;
    }
#pragma unroll
    for (int qi = 0; qi < 4; ++qi) {
      const int qt = qh * 4 + qi;
      short8 bq;
      if (quad < 2) {
        bq = *(const short8*)&S_bf[(size_t)(qt * 16 + col) * SROW + g * 16 + quad * 8];
      } else {
        bq = short8{0, 0, 0, 0, 0, 0, 0, 0};
      }
#pragma unroll
      for (int ft = 0; ft < 3; ++ft) {
        floatx4 c2 = mfma16h(h8(af[ft]), h8(bq), zf4);
        unsigned short* up =
            &Ub2[(size_t)(ft * 16 + quad * 4) * UFS + g * UGS + qt * 16 + col];
        if (ft < 2) {
#pragma unroll
          for (int r = 0; r < 4; ++r) up[r * UFS] = f16b(c2[r]);
        } else {
#pragma unroll
          for (int r = 0; r < 4; ++r)
            if (32 + quad * 4 + r < F0) up[r * UFS] = f16b(c2[r]);
        }
      }
    }
  }

  // ---- pre-issue phase-3's first W loads (3-deep, held across the ----
  // ---- barrier ONLY — 2b->3 barrier drain completes them for free) ----
  const int t3  = wv & 7;
  const int kh  = wv >> 3;
  const int cb0 = kh ? 20 : 0;
  const int cbN = kh ? F0 : 20;
  short8 rA[4], rB[4], rC[4];
#pragma unroll
  for (int i = 0; i < 4; ++i)
    rA[i] = wA2[(size_t)(((cb0 + 0) * 4 + i) * 8 + t3) * 64 + lane];
#pragma unroll
  for (int i = 0; i < 4; ++i)
    rB[i] = wA2[(size_t)(((cb0 + 1) * 4 + i) * 8 + t3) * 64 + lane];
#pragma unroll
  for (int i = 0; i < 4; ++i)
    rC[i] = wA2[(size_t)(((cb0 + 2) * 4 + i) * 8 + t3) * 64 + lane];
  __syncthreads();

  // ===== phase 3: wave = (t, kh). out2 = sum_c W1frag(c) x Ufrag(c) =====
  // B-frag: k = quad*8+j over p = cb*128 + i*32 + k -> Ub2[cb][g=col][i*32+quad*8..+8]
  {
    const short8 zero8 = {0, 0, 0, 0, 0, 0, 0, 0};
    floatx4 aco[4];
#pragma unroll
    for (int i = 0; i < 4; ++i) aco[i] = zf4;
    for (int cb = cb0; cb < cbN; ++cb) {
      const int cf = (cb + 3 < cbN) ? cb + 3 : cbN - 1;
      short8 nx[4];
#pragma unroll
      for (int i = 0; i < 4; ++i)
        nx[i] = wA2[(size_t)((cf * 4 + i) * 8 + t3) * 64 + lane];
      const unsigned short* ubase = &Ub2[(size_t)cb * UFS + col * UGS + quad * 8];
#pragma unroll
      for (int i = 0; i < 4; ++i) {
        short8 bU = (col < 8) ? *(const short8*)(ubase + i * 32) : zero8;
        aco[i] = mfma16h(h8(rA[i]), h8(bU), aco[i]);
      }
#pragma unroll
      for (int i = 0; i < 4; ++i) { rA[i] = rB[i]; rB[i] = rC[i]; rC[i] = nx[i]; }
    }
    float v[4];
#pragma unroll
    for (int r = 0; r < 4; ++r)
      v[r] = (aco[0][r] + aco[1][r]) + (aco[2][r] + aco[3][r]);

    // k-half reduction through S32 (xs dead; stride 9 -> <=2-way banks)
    if (kh == 0 && col < 8) {
#pragma unroll
      for (int r = 0; r < 4; ++r)
        S32[(size_t)(t3 * 16 + quad * 4 + r) * 9 + col] = v[r];
    }
    __syncthreads();
    if (kh == 1 && col < 8) {
#pragma unroll
      for (int r = 0; r < 4; ++r) {
        int h = t3 * 16 + quad * 4 + r;
        out[(size_t)(b0 + col) * 256 + 128 + h] = v[r] + S32[(size_t)h * 9 + col];
      }
    }
  }
}

// ---------- fp32 last-resort fallback ----------
__global__ __launch_bounds__(128) void cin_fused_fallback(const float* __restrict__ x,
                                                          const float* __restrict__ w0,
                                                          const float* __restrict__ w1,
                                                          float* __restrict__ out) {
  __shared__ float4 xs4[F0 * D_ / 4];
  __shared__ float4 h1s4[H_ * D_ / 4];
  __shared__ float4 z4[H_ * D_ / 4];
  const int tid = threadIdx.x;
  const int b = blockIdx.x;
  const int hh = tid >> 2, dd = tid & 3, h0 = hh << 2;
  {
    const float4* xg = (const float4*)(x + (size_t)b * (F0 * D_));
    for (int i = tid; i < F0 * D_ / 4; i += 128) xs4[i] = xg[i];
  }
  __syncthreads();
  float acc[4][4];
#pragma unroll
  for (int i = 0; i < 4; ++i)
#pragma unroll
    for (int j = 0; j < 4; ++j) acc[i][j] = 0.f;
  for (int f = 0; f < F0; ++f) {
    for (int i = tid; i < F0 * D_ / 4; i += 128) {
      float4 xv = xs4[(f << 2) + (i & 3)], qv = xs4[i];
      z4[i] = make_float4(xv.x * qv.x, xv.y * qv.y, xv.z * qv.z, xv.w * qv.w);
    }
    __syncthreads();
    for (int q = 0; q < F0; ++q) {
      float4 zv = z4[(q << 2) + dd];
      int p = f * F0 + q;
      float ww[4] = {w0[(h0 + 0) * P0_ + p], w0[(h0 + 1) * P0_ + p],
                     w0[(h0 + 2) * P0_ + p], w0[(h0 + 3) * P0_ + p]};
      float zz[4] = {zv.x, zv.y, zv.z, zv.w};
#pragma unroll
      for (int hi = 0; hi < 4; ++hi)
#pragma unroll
        for (int di = 0; di < 4; ++di) acc[hi][di] += ww[hi] * zz[di];
    }
    __syncthreads();
  }
#pragma unroll
  for (int hi = 0; hi < 4; ++hi)
    h1s4[(h0 + hi) * 4 + dd] = make_float4(acc[hi][0], acc[hi][1], acc[hi][2], acc[hi][3]);
  __syncthreads();
  {
    float4 a0 = h1s4[tid * 4 + 0], a1 = h1s4[tid * 4 + 1];
    float4 a2 = h1s4[tid * 4 + 2], a3 = h1s4[tid * 4 + 3];
    out[(size_t)b * 256 + tid] = (a0.x + a0.y + a0.z + a0.w) + (a1.x + a1.y + a1.z + a1.w) +
                                 (a2.x + a2.y + a2.z + a2.w) + (a3.x + a3.y + a3.z + a3.w);
  }
#pragma unroll
  for (int i = 0; i < 4; ++i)
#pragma unroll
    for (int j = 0; j < 4; ++j) acc[i][j] = 0.f;
  for (int f = 0; f < F0; ++f) {
    for (int i = tid; i < H_ * D_ / 4; i += 128) {
      float4 xv = xs4[(f << 2) + (i & 3)], hv = h1s4[i];
      z4[i] = make_float4(xv.x * hv.x, xv.y * hv.y, xv.z * hv.z, xv.w * hv.w);
    }
    __syncthreads();
    for (int q = 0; q < H_; ++q) {
      float4 zv = z4[(q << 2) + dd];
      int p = f * H_ + q;
      float ww[4] = {w1[(h0 + 0) * P1_ + p], w1[(h0 + 1) * P1_ + p],
                     w1[(h0 + 2) * P1_ + p], w1[(h0 + 3) * P1_ + p]};
      float zz[4] = {zv.x, zv.y, zv.z, zv.w};
#pragma unroll
      for (int hi = 0; hi < 4; ++hi)
#pragma unroll
        for (int di = 0; di < 4; ++di) acc[hi][di] += ww[hi] * zz[di];
    }
    __syncthreads();
  }
#pragma unroll
  for (int hi = 0; hi < 4; ++hi)
    z4[(h0 + hi) * 4 + dd] = make_float4(acc[hi][0], acc[hi][1], acc[hi][2], acc[hi][3]);
  __syncthreads();
  {
    float4 a0 = z4[tid * 4 + 0], a1 = z4[tid * 4 + 1];
    float4 a2 = z4[tid * 4 + 2], a3 = z4[tid * 4 + 3];
    out[(size_t)b * 256 + 128 + tid] = (a0.x + a0.y + a0.z + a0.w) + (a1.x + a1.y + a1.z + a1.w) +
                                       (a2.x + a2.y + a2.z + a2.w) + (a3.x + a3.y + a3.z + a3.w);
  }
}

extern "C" void kernel_launch(void* const* d_in, const int* in_sizes, int n_in,
                              void* d_out, int out_size, void* d_ws, size_t ws_size,
                              hipStream_t stream) {
  const float* x  = (const float*)d_in[0];
  const float* w0 = (const float*)d_in[1];
  const float* w1 = (const float*)d_in[2];
  float* out = (float*)d_out;

  const size_t nfr    = (size_t)(NF1 + NF2) * 64;   // 109824 (frag,lane) pairs
  const size_t wbytes = nfr * sizeof(short8);       // ~1.76 MB

  if (ws_size >= wbytes) {
    short8* wA1 = (short8*)d_ws;
    short8* wA2 = wA1 + (size_t)NF1 * 64;
    pack_w_kernel<<<256, 256, 0, stream>>>(w0, w1, wA1, wA2);
    cin_fused<<<256, 1024, 0, stream>>>(x, wA1, wA2, out);
  } else {
    cin_fused_fallback<<<2048, 128, 0, stream>>>(x, w0, w1, out);
  }
}

// Round 10
// 94.419 us; speedup vs baseline: 2.4263x; 1.0202x over previous
//
#include <hip/hip_runtime.h>

// CIN fully fused, d-contraction-first. R17 = R14 (best, 94.9us) + LDS
// operand prefetch rings: phase-3 reads cb+1's Ub2 B-frags before cb's
// MFMAs (was in-iteration: 4x ds_read_b128 -> immediate mfma, ~120cy
// exposed lgkm wait x 20 iters at only 4 waves/SIMD); phase-2b same for
// the S_bf bq operand. Phase-local registers only; global rings, layout,
// traffic all unchanged from R14. (R16's 3-deep global rings: neutral;
// R15 coop grid.sync: -110us, dead.)
//   out1[b,h] = sum_d h1[b,h,d];  h1 = sum_{f,q} W0[h,fq] x[b,f,d] x[b,q,d]
//   out2[b,h] = sum_p W1[h,p] U[b,p];  U[b,(f,q)] = sum_d x[b,f,d] h1[b,q,d]
// 256 blocks x 1024 thr, 1 block/CU, ~140KB LDS, fp16 datapath.

#define F0   39
#define D_   16
#define H_   128
#define P0_  1521
#define P1_  4992
#define G8   8
#define NF1  (F0 * 3 * 4)   // 468 layer-1 A-frags (f x ks x mt), 32x32x16
#define NF2  (F0 * 4 * 8)   // 1248 W1 A-frags (16x16x32)
#define SROW 136            // S_bf row stride in shorts (272B, 16B-aligned)
#define UGS  136            // Ub2 g-stride in shorts (272B: dw%32 = 4)
#define UFS  1096           // Ub2 f-stride in shorts (8*136+8; 2192B, 16B-aligned)

#define SBF_OFF   19968                        // xs = [0, 19968)
#define R_OFF     (SBF_OFF + 128 * SROW * 2)   // 54784: xTb / Ub2 region
#define XCH_OFF   (R_OFF + 16384)              // 71168: fp32 exchange (64KB)
#define SMEM_SZ   (R_OFF + F0 * UFS * 2)       // 140272

typedef __attribute__((ext_vector_type(8)))  short    short8;
typedef __attribute__((ext_vector_type(8)))  _Float16 half8;
typedef __attribute__((ext_vector_type(2)))  _Float16 half2v;
typedef __attribute__((ext_vector_type(4)))  float    floatx4;
typedef __attribute__((ext_vector_type(16))) float    floatx16;

__device__ __forceinline__ unsigned short f16b(float f) {
  return __builtin_bit_cast(unsigned short, (_Float16)f);
}

__device__ __forceinline__ unsigned int pkrtz(float a, float b) {
  return __builtin_bit_cast(unsigned int, __builtin_amdgcn_cvt_pkrtz(a, b));
}

__device__ __forceinline__ floatx4 mfma16h(half8 a, half8 b, floatx4 c) {
  return __builtin_amdgcn_mfma_f32_16x16x32_f16(a, b, c, 0, 0, 0);
}

__device__ __forceinline__ floatx16 mfma32h(half8 a, half8 b, floatx16 c) {
  return __builtin_amdgcn_mfma_f32_32x32x16_f16(a, b, c, 0, 0, 0);
}

__device__ __forceinline__ half8 h8(short8 s) {
  return __builtin_bit_cast(half8, s);
}

// ---------- pack W into MFMA A-frag order: one block per W row ----------
// wA1 (32x32x16): frag = (f*3 + ks)*4 + mt
//   A[m][k]: m = mt*32 + (lane&31), k = (lane>>5)*8 + j, q = ks*16 + k
//   -> row m supplies (f, ks, kg): frag=(f*3+ks)*4+(m>>5), lane=kg*32+(m&31)
// wA2 (16x16x32): frag = (f*4 + s)*8 + t, m = t*16+(lane&15)
//   -> row m supplies (f, s, quad): frag=(f*4+s)*8+(m>>4), lane=quad*16+(m&15)
__global__ __launch_bounds__(256) void pack_w_kernel(const float* __restrict__ w0,
                                                     const float* __restrict__ w1,
                                                     short8* __restrict__ wA1,
                                                     short8* __restrict__ wA2) {
  __shared__ float row[P1_];          // 19968B max
  const int tid = threadIdx.x;
  const int b   = blockIdx.x;
  if (b < H_) {
    const int m = b;
    const float* src = w0 + (size_t)m * P0_;
    for (int i = tid; i < P0_; i += 256) row[i] = src[i];   // coalesced dwords
    __syncthreads();
    const int mt = m >> 5, lr = m & 31;
    for (int it = tid; it < F0 * 3 * 2; it += 256) {        // 234 items
      int kg = it & 1;
      int ks = (it >> 1) % 3;
      int f  = it / 6;
      int frag = (f * 3 + ks) * 4 + mt;
      int lane = kg * 32 + lr;
      union { short8 v; unsigned int u[4]; } pk;
#pragma unroll
      for (int jj = 0; jj < 4; ++jj) {
        int q0 = ks * 16 + kg * 8 + jj * 2;
        float a = (q0     < F0) ? row[f * F0 + q0]     : 0.f;
        float c = (q0 + 1 < F0) ? row[f * F0 + q0 + 1] : 0.f;
        pk.u[jj] = pkrtz(a, c);
      }
      wA1[(size_t)frag * 64 + lane] = pk.v;
    }
  } else {
    const int m = b - H_;
    const float4* src4 = (const float4*)(w1 + (size_t)m * P1_);  // 19968B row
    float4* row4 = (float4*)row;
    for (int i = tid; i < P1_ / 4; i += 256) row4[i] = src4[i];  // coalesced float4
    __syncthreads();
    const int t = m >> 4, lc = m & 15;
    for (int it = tid; it < F0 * 16; it += 256) {           // 624 items
      int quad = it & 3;
      int s    = (it >> 2) & 3;
      int f    = it >> 4;
      int frag = (f * 4 + s) * 8 + t;
      int lane = quad * 16 + lc;
      const float* rp = &row[f * 128 + s * 32 + quad * 8];
      union { short8 v; unsigned int u[4]; } pk;
#pragma unroll
      for (int jj = 0; jj < 4; ++jj) pk.u[jj] = pkrtz(rp[jj * 2], rp[jj * 2 + 1]);
      wA2[(size_t)frag * 64 + lane] = pk.v;
    }
  }
}

// ---------- fused main kernel ----------
__global__ __launch_bounds__(1024, 4) void cin_fused(const float* __restrict__ x,
                                                     const short8* __restrict__ wA1,
                                                     const short8* __restrict__ wA2,
                                                     float* __restrict__ out) {
  // LDS: [0,19968) xs fp32 (reused as S32 in phase-3 reduce)
  //      [19968, +34816) S_bf (fp16)
  //      [54784, +16384) xTb (fp16, dies after phase-1 bq reads)
  //      [71168, +65536) Xch fp32 (phase-1 partial exchange)
  //      [54784, +85488) Ub2 (phase 2b/3; aliases xTb+Xch after barrier)
  __shared__ __align__(16) char smem[SMEM_SZ];
  float (*xs)[F0][D_]   = (float (*)[F0][D_])smem;
  float* S32            = (float*)smem;                       // phase 3 only
  unsigned short* S_bf  = (unsigned short*)(smem + SBF_OFF);  // [128][SROW]
  unsigned short* xTb   = (unsigned short*)(smem + R_OFF);
  unsigned short* Ub2   = xTb;                                // aliased
  float4*        Xch4   = (float4*)(smem + XCH_OFF);

  const int tid  = threadIdx.x;
  const int lane = tid & 63;
  const int wv   = tid >> 6;      // 16 waves
  const int col  = lane & 15;
  const int quad = lane >> 4;
  const int b0   = blockIdx.x * G8;
  const floatx4 zf4 = {0.f, 0.f, 0.f, 0.f};
  const short8 zero8 = {0, 0, 0, 0, 0, 0, 0, 0};

  // ---- phase-1 wave coords (early, for top-of-kernel A prefetch) ----
  const int mt  = wv & 3;          // h-tile of 32
  const int gp2 = (wv >> 2) & 1;   // batch quad selector
  const int fh2 = wv >> 3;         // f-half
  const int fB  = fh2 ? 20 : 0;
  const int fE  = fh2 ? F0 : 20;

  // issue the first two f's A-frags now; latency hides under x staging
  short8 a0 = wA1[(size_t)((fB * 3 + 0) * 4 + mt) * 64 + lane];
  short8 a1 = wA1[(size_t)((fB * 3 + 1) * 4 + mt) * 64 + lane];
  short8 a2 = wA1[(size_t)((fB * 3 + 2) * 4 + mt) * 64 + lane];
  short8 p0 = wA1[(size_t)(((fB + 1) * 3 + 0) * 4 + mt) * 64 + lane];
  short8 p1 = wA1[(size_t)(((fB + 1) * 3 + 1) * 4 + mt) * 64 + lane];
  short8 p2 = wA1[(size_t)(((fB + 1) * 3 + 2) * 4 + mt) * 64 + lane];

  // ---- stage x (coalesced float4) ----
  {
    const float4* xg = (const float4*)(x + (size_t)b0 * (F0 * D_));
    float4* xl = (float4*)smem;
    for (int i = tid; i < G8 * F0 * D_ / 4; i += 1024) xl[i] = xg[i];
  }
  __syncthreads();

  // ---- xTb[g][q8][d][j] = f16(x[g][q8*8+j][d]), zero-pad q>=39 ----
  {
    int i = tid;                      // exactly 1024 = G8*8*16 entries
    int d = i & 15, q8 = (i >> 4) & 7, g = i >> 7;
    union { short8 v; unsigned int u[4]; } pk;
#pragma unroll
    for (int jj = 0; jj < 4; ++jj) {
      int qa = q8 * 8 + jj * 2, qb = qa + 1;
      float va = (qa < F0) ? xs[g][qa][d] : 0.f;
      float vb = (qb < F0) ? xs[g][qb][d] : 0.f;
      pk.u[jj] = pkrtz(va, vb);
    }
    *(short8*)&xTb[(size_t)i * 8] = pk.v;
  }
  __syncthreads();

  // ===== phase 1: 32x32x16 f16; wave = (fh2, gp2, mt). Two g-pair tiles =====
  // per f: acc = mfma(W0frag, bq * f16(x[g,f,d]), acc) x3 — scale folded
  // into B via v_pk_mul_f16, MFMA accumulates directly.
  {
    const int c32 = lane & 31;       // C col: n = g_local*16 + d
    const int kg  = lane >> 5;       // k half (8 q's each)
    const int d   = c32 & 15;
    const int gU  = gp2 * 4 + (c32 >> 4);
    const int gV  = gU + 2;

    // B[n][k]: n = c32, k = kg*8+j, q = ks*16 + k  ->  xTb[g][ks*2+kg][d][j]
    half8 bu0 = h8(*(const short8*)&xTb[(size_t)(((gU * 8 + 0 + kg) * 16) + d) * 8]);
    half8 bu1 = h8(*(const short8*)&xTb[(size_t)(((gU * 8 + 2 + kg) * 16) + d) * 8]);
    half8 bu2 = h8(*(const short8*)&xTb[(size_t)(((gU * 8 + 4 + kg) * 16) + d) * 8]);
    half8 bv0 = h8(*(const short8*)&xTb[(size_t)(((gV * 8 + 0 + kg) * 16) + d) * 8]);
    half8 bv1 = h8(*(const short8*)&xTb[(size_t)(((gV * 8 + 2 + kg) * 16) + d) * 8]);
    half8 bv2 = h8(*(const short8*)&xTb[(size_t)(((gV * 8 + 4 + kg) * 16) + d) * 8]);

    floatx16 accU = {0.f, 0.f, 0.f, 0.f, 0.f, 0.f, 0.f, 0.f,
                     0.f, 0.f, 0.f, 0.f, 0.f, 0.f, 0.f, 0.f};
    floatx16 accV = accU;

    for (int f = fB; f < fE; ++f) {
      const int f2 = (f + 2 < fE) ? f + 2 : fE - 1;
      short8 n0 = wA1[(size_t)((f2 * 3 + 0) * 4 + mt) * 64 + lane];
      short8 n1 = wA1[(size_t)((f2 * 3 + 1) * 4 + mt) * 64 + lane];
      short8 n2 = wA1[(size_t)((f2 * 3 + 2) * 4 + mt) * 64 + lane];
      const _Float16 hU = (_Float16)xs[gU][f][d];
      const _Float16 hV = (_Float16)xs[gV][f][d];
      accU = mfma32h(h8(a0), bu0 * hU, accU);
      accV = mfma32h(h8(a0), bv0 * hV, accV);
      accU = mfma32h(h8(a1), bu1 * hU, accU);
      accV = mfma32h(h8(a1), bv1 * hV, accV);
      accU = mfma32h(h8(a2), bu2 * hU, accU);
      accV = mfma32h(h8(a2), bv2 * hV, accV);
      a0 = p0; a1 = p1; a2 = p2;
      p0 = n0; p1 = n1; p2 = n2;
    }

    // ---- f-half partial exchange (fp32 float4, conflict-free) ----
    const int wid = gp2 * 4 + mt;    // 0..7, shared by the fh2 pair
    if (fh2 == 0) {
#pragma unroll
      for (int seg = 0; seg < 4; ++seg) {
        float4 u4 = make_float4(accU[seg * 4 + 0], accU[seg * 4 + 1],
                                accU[seg * 4 + 2], accU[seg * 4 + 3]);
        Xch4[(size_t)((wid * 8 + seg) * 64) + lane] = u4;
        float4 v4 = make_float4(accV[seg * 4 + 0], accV[seg * 4 + 1],
                                accV[seg * 4 + 2], accV[seg * 4 + 3]);
        Xch4[(size_t)((wid * 8 + 4 + seg) * 64) + lane] = v4;
      }
    }
    __syncthreads();
    if (fh2 == 1) {
#pragma unroll
      for (int seg = 0; seg < 4; ++seg) {
        float4 u4 = Xch4[(size_t)((wid * 8 + seg) * 64) + lane];
        accU[seg * 4 + 0] += u4.x; accU[seg * 4 + 1] += u4.y;
        accU[seg * 4 + 2] += u4.z; accU[seg * 4 + 3] += u4.w;
        float4 v4 = Xch4[(size_t)((wid * 8 + 4 + seg) * 64) + lane];
        accV[seg * 4 + 0] += v4.x; accV[seg * 4 + 1] += v4.y;
        accV[seg * 4 + 2] += v4.z; accV[seg * 4 + 3] += v4.w;
      }
      // final h1 -> S_bf (f16). Row = mt*32 + ((r&3)+8*(r>>2)+4*kg).
#pragma unroll
      for (int r = 0; r < 16; ++r) {
        const int row = (r & 3) + 8 * (r >> 2) + 4 * kg;
        S_bf[(size_t)(mt * 32 + row) * SROW + (gp2 * 2 + 0) * 32 + c32] = f16b(accU[r]);
        S_bf[(size_t)(mt * 32 + row) * SROW + (gp2 * 2 + 1) * 32 + c32] = f16b(accV[r]);
      }
    }
  }
  __syncthreads();

  // ===== phase 2a: out1[b,h] = sum_d h1 (1024 threads, one shot) =====
  {
    int h = tid & 127, g = tid >> 7;
    union { short8 v; unsigned int u[4]; } w0v, w1v;
    w0v.v = *(const short8*)&S_bf[(size_t)h * SROW + g * 16];
    w1v.v = *(const short8*)&S_bf[(size_t)h * SROW + g * 16 + 8];
    float sum = 0.f;
#pragma unroll
    for (int p = 0; p < 4; ++p) {
      half2v h0 = __builtin_bit_cast(half2v, w0v.u[p]);
      half2v h1 = __builtin_bit_cast(half2v, w1v.u[p]);
      sum += (float)h0[0] + (float)h0[1] + (float)h1[0] + (float)h1[1];
    }
    out[(size_t)(b0 + g) * 256 + h] = sum;
  }

  // ===== phase 2b: wave = (g, qh). U[g,(f,q)] = sum_d x[g,f,d] h1[g,q,d] =====
  // MFMA: A[m=f][k=d], B[n=q][k=d] -> C[m=f][n=q].
  // bq (S_bf operand) prefetched 1 qt ahead. Store to Ub2[f][g][q] (f16).
  {
    const int g  = wv & 7;
    const int qh = wv >> 3;
    short8 af[3];
#pragma unroll
    for (int ft = 0; ft < 3; ++ft) {
      union { short8 v; unsigned int u[4]; } pk;
      int f = ft * 16 + col;
      if (quad < 2 && f < F0) {
        const float4* xp = (const float4*)&xs[g][f][quad * 8];
        float4 x0 = xp[0], x1 = xp[1];
        pk.u[0] = pkrtz(x0.x, x0.y);
        pk.u[1] = pkrtz(x0.z, x0.w);
        pk.u[2] = pkrtz(x1.x, x1.y);
        pk.u[3] = pkrtz(x1.z, x1.w);
      } else {
        pk.u[0] = pk.u[1] = pk.u[2] = pk.u[3] = 0u;
      }
      af[ft] = pk.v;
    }
    short8 bq = zero8;
    if (quad < 2)
      bq = *(const short8*)&S_bf[(size_t)((qh * 4) * 16 + col) * SROW + g * 16 + quad * 8];
#pragma unroll
    for (int qi = 0; qi < 4; ++qi) {
      const int qt = qh * 4 + qi;
      short8 nbq = zero8;
      if (qi < 3 && quad < 2)
        nbq = *(const short8*)&S_bf[(size_t)((qt + 1) * 16 + col) * SROW + g * 16 + quad * 8];
#pragma unroll
      for (int ft = 0; ft < 3; ++ft) {
        floatx4 c2 = mfma16h(h8(af[ft]), h8(bq), zf4);
        unsigned short* up =
            &Ub2[(size_t)(ft * 16 + quad * 4) * UFS + g * UGS + qt * 16 + col];
        if (ft < 2) {
#pragma unroll
          for (int r = 0; r < 4; ++r) up[r * UFS] = f16b(c2[r]);
        } else {
#pragma unroll
          for (int r = 0; r < 4; ++r)
            if (32 + quad * 4 + r < F0) up[r * UFS] = f16b(c2[r]);
        }
      }
      bq = nbq;
    }
  }

  // ---- pre-issue phase-3's first W loads; 2b->3 barrier drain completes ----
  const int t3  = wv & 7;
  const int kh  = wv >> 3;
  const int cb0 = kh ? 20 : 0;
  const int cbN = kh ? F0 : 20;
  short8 aW[4], aX[4];
#pragma unroll
  for (int i = 0; i < 4; ++i)
    aW[i] = wA2[(size_t)((cb0 * 4 + i) * 8 + t3) * 64 + lane];
#pragma unroll
  for (int i = 0; i < 4; ++i)
    aX[i] = wA2[(size_t)(((cb0 + 1) * 4 + i) * 8 + t3) * 64 + lane];
  __syncthreads();

  // ===== phase 3: wave = (t, kh). out2 = sum_c W1frag(c) x Ufrag(c) =====
  // B-frag: k = quad*8+j over p = cb*128 + i*32 + k -> Ub2[cb][g=col][i*32+quad*8..+8]
  // bU (Ub2 operand) prefetched 1 cb ahead; W ring 2-deep as R14.
  {
    floatx4 aco[4];
#pragma unroll
    for (int i = 0; i < 4; ++i) aco[i] = zf4;
    short8 bU[4];
    {
      const unsigned short* ub0 = &Ub2[(size_t)cb0 * UFS + col * UGS + quad * 8];
#pragma unroll
      for (int i = 0; i < 4; ++i)
        bU[i] = (col < 8) ? *(const short8*)(ub0 + i * 32) : zero8;
    }
    for (int cb = cb0; cb < cbN; ++cb) {
      const int c2i = (cb + 2 < cbN) ? cb + 2 : cbN - 1;
      short8 nx[4];
#pragma unroll
      for (int i = 0; i < 4; ++i)
        nx[i] = wA2[(size_t)((c2i * 4 + i) * 8 + t3) * 64 + lane];
      const int cn = (cb + 1 < cbN) ? cb + 1 : cb;
      const unsigned short* ubn = &Ub2[(size_t)cn * UFS + col * UGS + quad * 8];
      short8 nbU[4];
#pragma unroll
      for (int i = 0; i < 4; ++i)
        nbU[i] = (col < 8) ? *(const short8*)(ubn + i * 32) : zero8;
#pragma unroll
      for (int i = 0; i < 4; ++i)
        aco[i] = mfma16h(h8(aW[i]), h8(bU[i]), aco[i]);
#pragma unroll
      for (int i = 0; i < 4; ++i) { aW[i] = aX[i]; aX[i] = nx[i]; bU[i] = nbU[i]; }
    }
    float v[4];
#pragma unroll
    for (int r = 0; r < 4; ++r)
      v[r] = (aco[0][r] + aco[1][r]) + (aco[2][r] + aco[3][r]);

    // k-half reduction through S32 (xs dead; stride 9 -> <=2-way banks)
    if (kh == 0 && col < 8) {
#pragma unroll
      for (int r = 0; r < 4; ++r)
        S32[(size_t)(t3 * 16 + quad * 4 + r) * 9 + col] = v[r];
    }
    __syncthreads();
    if (kh == 1 && col < 8) {
#pragma unroll
      for (int r = 0; r < 4; ++r) {
        int h = t3 * 16 + quad * 4 + r;
        out[(size_t)(b0 + col) * 256 + 128 + h] = v[r] + S32[(size_t)h * 9 + col];
      }
    }
  }
}

// ---------- fp32 last-resort fallback ----------
__global__ __launch_bounds__(128) void cin_fused_fallback(const float* __restrict__ x,
                                                          const float* __restrict__ w0,
                                                          const float* __restrict__ w1,
                                                          float* __restrict__ out) {
  __shared__ float4 xs4[F0 * D_ / 4];
  __shared__ float4 h1s4[H_ * D_ / 4];
  __shared__ float4 z4[H_ * D_ / 4];
  const int tid = threadIdx.x;
  const int b = blockIdx.x;
  const int hh = tid >> 2, dd = tid & 3, h0 = hh << 2;
  {
    const float4* xg = (const float4*)(x + (size_t)b * (F0 * D_));
    for (int i = tid; i < F0 * D_ / 4; i += 128) xs4[i] = xg[i];
  }
  __syncthreads();
  float acc[4][4];
#pragma unroll
  for (int i = 0; i < 4; ++i)
#pragma unroll
    for (int j = 0; j < 4; ++j) acc[i][j] = 0.f;
  for (int f = 0; f < F0; ++f) {
    for (int i = tid; i < F0 * D_ / 4; i += 128) {
      float4 xv = xs4[(f << 2) + (i & 3)], qv = xs4[i];
      z4[i] = make_float4(xv.x * qv.x, xv.y * qv.y, xv.z * qv.z, xv.w * qv.w);
    }
    __syncthreads();
    for (int q = 0; q < F0; ++q) {
      float4 zv = z4[(q << 2) + dd];
      int p = f * F0 + q;
      float ww[4] = {w0[(h0 + 0) * P0_ + p], w0[(h0 + 1) * P0_ + p],
                     w0[(h0 + 2) * P0_ + p], w0[(h0 + 3) * P0_ + p]};
      float zz[4] = {zv.x, zv.y, zv.z, zv.w};
#pragma unroll
      for (int hi = 0; hi < 4; ++hi)
#pragma unroll
        for (int di = 0; di < 4; ++di) acc[hi][di] += ww[hi] * zz[di];
    }
    __syncthreads();
  }
#pragma unroll
  for (int hi = 0; hi < 4; ++hi)
    h1s4[(h0 + hi) * 4 + dd] = make_float4(acc[hi][0], acc[hi][1], acc[hi][2], acc[hi][3]);
  __syncthreads();
  {
    float4 a0 = h1s4[tid * 4 + 0], a1 = h1s4[tid * 4 + 1];
    float4 a2 = h1s4[tid * 4 + 2], a3 = h1s4[tid * 4 + 3];
    out[(size_t)b * 256 + tid] = (a0.x + a0.y + a0.z + a0.w) + (a1.x + a1.y + a1.z + a1.w) +
                                 (a2.x + a2.y + a2.z + a2.w) + (a3.x + a3.y + a3.z + a3.w);
  }
#pragma unroll
  for (int i = 0; i < 4; ++i)
#pragma unroll
    for (int j = 0; j < 4; ++j) acc[i][j] = 0.f;
  for (int f = 0; f < F0; ++f) {
    for (int i = tid; i < H_ * D_ / 4; i += 128) {
      float4 xv = xs4[(f << 2) + (i & 3)], hv = h1s4[i];
      z4[i] = make_float4(xv.x * hv.x, xv.y * hv.y, xv.z * hv.z, xv.w * hv.w);
    }
    __syncthreads();
    for (int q = 0; q < H_; ++q) {
      float4 zv = z4[(q << 2) + dd];
      int p = f * H_ + q;
      float ww[4] = {w1[(h0 + 0) * P1_ + p], w1[(h0 + 1) * P1_ + p],
                     w1[(h0 + 2) * P1_ + p], w1[(h0 + 3) * P1_ + p]};
      float zz[4] = {zv.x, zv.y, zv.z, zv.w};
#pragma unroll
      for (int hi = 0; hi < 4; ++hi)
#pragma unroll
        for (int di = 0; di < 4; ++di) acc[hi][di] += ww[hi] * zz[di];
    }
    __syncthreads();
  }
#pragma unroll
  for (int hi = 0; hi < 4; ++hi)
    z4[(h0 + hi) * 4 + dd] = make_float4(acc[hi][0], acc[hi][1], acc[hi][2], acc[hi][3]);
  __syncthreads();
  {
    float4 a0 = z4[tid * 4 + 0], a1 = z4[tid * 4 + 1];
    float4 a2 = z4[tid * 4 + 2], a3 = z4[tid * 4 + 3];
    out[(size_t)b * 256 + 128 + tid] = (a0.x + a0.y + a0.z + a0.w) + (a1.x + a1.y + a1.z + a1.w) +
                                       (a2.x + a2.y + a2.z + a2.w) + (a3.x + a3.y + a3.z + a3.w);
  }
}

extern "C" void kernel_launch(void* const* d_in, const int* in_sizes, int n_in,
                              void* d_out, int out_size, void* d_ws, size_t ws_size,
                              hipStream_t stream) {
  const float* x  = (const float*)d_in[0];
  const float* w0 = (const float*)d_in[1];
  const float* w1 = (const float*)d_in[2];
  float* out = (float*)d_out;

  const size_t nfr    = (size_t)(NF1 + NF2) * 64;   // 109824 (frag,lane) pairs
  const size_t wbytes = nfr * sizeof(short8);       // ~1.76 MB

  if (ws_size >= wbytes) {
    short8* wA1 = (short8*)d_ws;
    short8* wA2 = wA1 + (size_t)NF1 * 64;
    pack_w_kernel<<<256, 256, 0, stream>>>(w0, w1, wA1, wA2);
    cin_fused<<<256, 1024, 0, stream>>>(x, wA1, wA2, out);
  } else {
    cin_fused_fallback<<<2048, 128, 0, stream>>>(x, w0, w1, out);
  }
}